// Round 1
// baseline (1335.101 us; speedup 1.0000x reference)
//
#include <hip/hip_runtime.h>
#include <hip/hip_bf16.h>

// Problem constants
#define B_    16
#define T_    1000
#define FEAT  771
#define FEATP 776      // 771 padded to multiple of 8 (16B-aligned fp16 rows)
#define H_    512
#define H3    1536
#define KN_   9
#define KHID  4608     // H*KN
#define M_    16000    // B*T
#define NOUT  257      // output column slice [257:514)

typedef _Float16 half8 __attribute__((ext_vector_type(8)));
typedef float    floatx4 __attribute__((ext_vector_type(4)));

__device__ inline half8 h8zero() {
    half8 v;
    #pragma unroll
    for (int i = 0; i < 8; ++i) v[i] = (_Float16)0.f;
    return v;
}

// tanh(z) = 1 - 2/(1+e^{2z})  — saturates correctly at +/-inf, no NaN
__device__ inline float tanh_fast(float z) {
    return 1.0f - 2.0f / (1.0f + __expf(2.0f * z));
}
__device__ inline float sigmoid_fast(float z) {
    return 1.0f / (1.0f + __expf(-z));
}

// ---------------------------------------------------------------------------
// fp32 -> fp16 convert of inputs, padding rows 771 -> 776 with zeros
__global__ void convert_inputs(const float* __restrict__ in, _Float16* __restrict__ A1) {
    size_t i = (size_t)blockIdx.x * 256 + threadIdx.x;
    if (i >= (size_t)M_ * FEATP) return;
    size_t r = i / FEATP;
    int   cc = (int)(i % FEATP);
    A1[i] = (cc < FEAT) ? (_Float16)in[r * FEAT + cc] : (_Float16)0.f;
}

// ---------------------------------------------------------------------------
// LDS-tiled transpose+convert: Wt[n*Kp + k] = (k<K) ? W[k*ldw + coloff + n] : 0
__global__ __launch_bounds__(256) void transpose_w(
    const float* __restrict__ W, _Float16* __restrict__ Wt,
    int K, int N, int ldw, int coloff, int Kp)
{
    __shared__ float tile[32][33];
    const int kb = blockIdx.x * 32;
    const int nb = blockIdx.y * 32;
    const int tx = threadIdx.x & 31;
    const int ty = threadIdx.x >> 5;   // 0..7
    #pragma unroll
    for (int r = ty; r < 32; r += 8) {
        const int k = kb + r, n = nb + tx;
        tile[r][tx] = (k < K && n < N) ? W[(size_t)k * ldw + coloff + n] : 0.f;
    }
    __syncthreads();
    #pragma unroll
    for (int r = ty; r < 32; r += 8) {
        const int n = nb + r, k = kb + tx;
        if (n < N && k < Kp) Wt[(size_t)n * Kp + k] = (_Float16)tile[tx][r];
    }
}

// ---------------------------------------------------------------------------
// Tiled fp16 MFMA GEMM: C[M x N] = A[M x Kp] * Bt[N x Kp]^T, fp32 accumulate.
// 128x128 block tile, BK=32, 4 waves (2x2), each wave 4x4 of 16x16x32 MFMA.
// M is always a multiple of 128 (16000 = 125*128) -> no M bounds checks.
// Zero-pad beyond Kp handled by staging; rows >= Nb zero-filled.
// EPI: 0 = tanh(+bias) -> fp16 ; 1 = raw -> fp16 ; 2 = sigmoid(+bias)*aux -> fp32 out
template <int EPI>
__global__ __launch_bounds__(256) void gemm_kernel(
    const _Float16* __restrict__ A, const _Float16* __restrict__ Bt,
    int Kp, int nk, int Nb,
    _Float16* __restrict__ Ch, float* __restrict__ Cf, int ldc,
    const float* __restrict__ bias, const float* __restrict__ aux)
{
    __shared__ __align__(16) _Float16 As[128][40];  // +8 pad, 16B-aligned rows
    __shared__ __align__(16) _Float16 Bs[128][40];

    const int tid  = threadIdx.x;
    const int m0   = blockIdx.x * 128;
    const int n0   = blockIdx.y * 128;
    const int wave = tid >> 6;
    const int lane = tid & 63;
    const int wr   = (wave >> 1) << 6;   // wave row offset (0/64)
    const int wc   = (wave & 1) << 6;    // wave col offset (0/64)
    const int lrow = lane & 15;
    const int lq   = lane >> 4;          // 0..3
    const int srow = tid >> 1;           // staging row 0..127
    const int scol = (tid & 1) << 4;     // staging col 0 or 16

    floatx4 acc[4][4];
    #pragma unroll
    for (int i = 0; i < 4; ++i)
        #pragma unroll
        for (int j = 0; j < 4; ++j)
            #pragma unroll
            for (int r = 0; r < 4; ++r) acc[i][j][r] = 0.f;

    const _Float16* aRow = A + (size_t)(m0 + srow) * Kp;
    const int  brow   = n0 + srow;
    const _Float16* bRow = Bt + (size_t)brow * Kp;
    const bool bvalid = (brow < Nb);

    for (int kc = 0; kc < nk; ++kc) {
        const int k0 = kc << 5;
        __syncthreads();
        #pragma unroll
        for (int s = 0; s < 2; ++s) {
            const int kk = k0 + scol + s * 8;
            half8 va = h8zero(), vb = h8zero();
            const bool kin = (kk + 8 <= Kp);
            if (kin)           va = *(const half8*)(aRow + kk);
            if (kin && bvalid) vb = *(const half8*)(bRow + kk);
            *(half8*)(&As[srow][scol + s * 8]) = va;
            *(half8*)(&Bs[srow][scol + s * 8]) = vb;
        }
        __syncthreads();

        half8 af[4], bfr[4];
        #pragma unroll
        for (int i = 0; i < 4; ++i) af[i]  = *(const half8*)(&As[wr + i * 16 + lrow][lq * 8]);
        #pragma unroll
        for (int j = 0; j < 4; ++j) bfr[j] = *(const half8*)(&Bs[wc + j * 16 + lrow][lq * 8]);
        #pragma unroll
        for (int i = 0; i < 4; ++i)
            #pragma unroll
            for (int j = 0; j < 4; ++j)
                acc[i][j] = __builtin_amdgcn_mfma_f32_16x16x32_f16(af[i], bfr[j], acc[i][j], 0, 0, 0);
    }

    // Epilogue: C/D layout col=lane&15, row=quad*4+reg
    #pragma unroll
    for (int j = 0; j < 4; ++j) {
        const int col = n0 + wc + j * 16 + lrow;
        if (col >= Nb) continue;
        #pragma unroll
        for (int i = 0; i < 4; ++i) {
            #pragma unroll
            for (int r = 0; r < 4; ++r) {
                const int row = m0 + wr + i * 16 + lq * 4 + r;
                float v = acc[i][j][r];
                if constexpr (EPI == 0) {
                    float z = v + bias[col];
                    Ch[(size_t)row * ldc + col] = (_Float16)tanh_fast(z);
                } else if constexpr (EPI == 1) {
                    Ch[(size_t)row * ldc + col] = (_Float16)v;
                } else {
                    float z = v + bias[col];
                    Cf[(size_t)row * NOUT + col] = sigmoid_fast(z) * aux[(size_t)row * FEAT + 257 + col];
                }
            }
        }
    }
}

// ---------------------------------------------------------------------------
// SRU scan: 8192 chains (b,h), sequential over t. Gates use OLD c (reference).
__global__ __launch_bounds__(64) void sru_scan(
    const _Float16* __restrict__ U, const _Float16* __restrict__ Xin,
    _Float16* __restrict__ Xout, const float* __restrict__ v, const float* __restrict__ bg)
{
    const int gid = blockIdx.x * 64 + threadIdx.x;
    const int b = gid >> 9;
    const int h = gid & 511;
    const float vf = v[h],      vr = v[512 + h];
    const float bf = bg[h],     br = bg[512 + h];
    float c = 0.f;
    const _Float16* Ub = U   + (size_t)b * T_ * H3 + h;
    const _Float16* Xb = Xin + (size_t)b * T_ * H_ + h;
    _Float16*       Ob = Xout + (size_t)b * T_ * H_ + h;
    for (int t = 0; t < T_; ++t) {
        const float xt = (float)Ub[0];
        const float fp = (float)Ub[512];
        const float rp = (float)Ub[1024];
        const float x  = (float)Xb[0];
        const float f  = sigmoid_fast(fp + vf * c + bf);
        const float r  = sigmoid_fast(rp + vr * c + br);
        const float cn = f * c + (1.0f - f) * xt;
        const float hO = r * cn + (1.0f - r) * x;
        *Ob = (_Float16)hO;
        c = cn;
        Ub += H3; Xb += H_; Ob += H_;
    }
}

// ---------------------------------------------------------------------------
// Fused conv6x6(asym pad 3,2) + bias + tanh + maxpool3x3(pad 1), writing the
// pooled result directly in (b*T+t, h*9+k) fp16 layout for the final GEMM.
__global__ __launch_bounds__(256) void conv_pool(
    const _Float16* __restrict__ X, const float* __restrict__ ck,
    const float* __restrict__ cb, _Float16* __restrict__ A3)
{
    __shared__ float in_s[23][72];        // input patch t0-4..t0+18, h0-4..h0+66
    __shared__ float cv[9][18][68];       // tanh(conv) for pool window (-1e30 = outside image)
    __shared__ float ck_s[324];
    __shared__ float cb_s[9];
    const int tid = threadIdx.x;
    int bi = blockIdx.x;
    const int th = bi & 7;  bi >>= 3;
    const int tt = bi % 63;
    const int b  = bi / 63;
    const int t0 = tt * 16, h0 = th * 64;

    for (int i = tid; i < 324; i += 256) ck_s[i] = ck[i];
    if (tid < 9) cb_s[tid] = cb[tid];

    for (int i = tid; i < 23 * 71; i += 256) {
        const int r = i / 71, cc = i % 71;
        const int gt = t0 - 4 + r, gh = h0 - 4 + cc;
        float val = 0.f;   // conv zero-padding
        if (gt >= 0 && gt < T_ && gh >= 0 && gh < H_)
            val = (float)X[((size_t)b * T_ + gt) * H_ + gh];
        in_s[r][cc] = val;
    }
    __syncthreads();

    for (int i = tid; i < 18 * 66 * 9; i += 256) {
        const int k  = i / 1188;
        const int p  = i % 1188;
        const int pt = p / 66, ph = p % 66;
        const int gt = t0 - 1 + pt, gh = h0 - 1 + ph;
        float r;
        if (gt >= 0 && gt < T_ && gh >= 0 && gh < H_) {
            float s = cb_s[k];
            const float* w = ck_s + k * 36;
            #pragma unroll
            for (int ii = 0; ii < 6; ++ii)
                #pragma unroll
                for (int jj = 0; jj < 6; ++jj)
                    s += w[ii * 6 + jj] * in_s[pt + ii][ph + jj];
            r = tanh_fast(s);
        } else {
            r = -1e30f;   // outside image: excluded from pool max
        }
        cv[k][pt][ph] = r;
    }
    __syncthreads();

    for (int i = tid; i < 16 * 64; i += 256) {
        const int pt = i >> 6, ph = i & 63;
        const int gt = t0 + pt;
        if (gt >= T_) continue;
        const int gh = h0 + ph;
        _Float16* dst = A3 + ((size_t)b * T_ + gt) * KHID + gh * KN_;
        #pragma unroll
        for (int k = 0; k < 9; ++k) {
            float m = cv[k][pt][ph];
            m = fmaxf(m, cv[k][pt][ph + 1]);
            m = fmaxf(m, cv[k][pt][ph + 2]);
            m = fmaxf(m, cv[k][pt + 1][ph]);
            m = fmaxf(m, cv[k][pt + 1][ph + 1]);
            m = fmaxf(m, cv[k][pt + 1][ph + 2]);
            m = fmaxf(m, cv[k][pt + 2][ph]);
            m = fmaxf(m, cv[k][pt + 2][ph + 1]);
            m = fmaxf(m, cv[k][pt + 2][ph + 2]);
            dst[k] = (_Float16)m;
        }
    }
}

// ---------------------------------------------------------------------------
extern "C" void kernel_launch(void* const* d_in, const int* in_sizes, int n_in,
                              void* d_out, int out_size, void* d_ws, size_t ws_size,
                              hipStream_t stream) {
    const float* inputs = (const float*)d_in[0];
    const float* W_in   = (const float*)d_in[1];
    const float* b_in   = (const float*)d_in[2];
    const float* W_rnn  = (const float*)d_in[3];
    const float* v_rnn  = (const float*)d_in[4];
    const float* b_rnn  = (const float*)d_in[5];
    const float* conv_k = (const float*)d_in[6];
    const float* conv_b = (const float*)d_in[7];
    const float* W_out  = (const float*)d_in[8];
    const float* b_out  = (const float*)d_in[9];
    float* out = (float*)d_out;

    char* ws = (char*)d_ws;
    size_t off = 0;
    auto take = [&](size_t bytes) -> char* {
        off = (off + 255) & ~(size_t)255;
        char* p = ws + off;
        off += bytes;
        return p;
    };
    _Float16* A1   = (_Float16*)take((size_t)M_ * FEATP * 2);   // inputs fp16, padded
    _Float16* W1T  = (_Float16*)take((size_t)H_ * FEATP * 2);   // W_in^T
    _Float16* W2T0 = (_Float16*)take((size_t)H3 * H_ * 2);      // W_rnn[0]^T
    _Float16* W2T1 = (_Float16*)take((size_t)H3 * H_ * 2);      // W_rnn[1]^T
    _Float16* W3T  = (_Float16*)take((size_t)NOUT * KHID * 2);  // W_out[:,257:514]^T
    _Float16* X0   = (_Float16*)take((size_t)M_ * H_ * 2);
    _Float16* X1   = (_Float16*)take((size_t)M_ * H_ * 2);
    _Float16* U    = (_Float16*)take((size_t)M_ * H3 * 2);
    _Float16* A3   = (_Float16*)take((size_t)M_ * KHID * 2);    // pooled conv, (h*9+k) layout
    _Float16* X2   = X0;  // X0 dead after scan layer 0 -> reuse

    // --- weight/input preprocessing (fp32 -> fp16, transpose to NxK) ---
    {
        size_t n = (size_t)M_ * FEATP;
        convert_inputs<<<dim3((unsigned)((n + 255) / 256)), 256, 0, stream>>>(inputs, A1);
    }
    transpose_w<<<dim3(25, 16), 256, 0, stream>>>(W_in, W1T, FEAT, H_, H_, 0, FEATP);
    transpose_w<<<dim3(16, 48), 256, 0, stream>>>(W_rnn, W2T0, H_, H3, H3, 0, H_);
    transpose_w<<<dim3(16, 48), 256, 0, stream>>>(W_rnn + (size_t)H_ * H3, W2T1, H_, H3, H3, 0, H_);
    transpose_w<<<dim3(144, 9), 256, 0, stream>>>(W_out, W3T, KHID, NOUT, FEAT, 257, KHID);

    // --- G1: X0 = tanh(inputs @ W_in + b_in) ---
    gemm_kernel<0><<<dim3(125, 4), 256, 0, stream>>>(A1, W1T, FEATP, 25, H_, X0, nullptr, H_, b_in, nullptr);

    // --- SRU layer 0 ---
    gemm_kernel<1><<<dim3(125, 12), 256, 0, stream>>>(X0, W2T0, H_, 16, H3, U, nullptr, H3, nullptr, nullptr);
    sru_scan<<<dim3(128), 64, 0, stream>>>(U, X0, X1, v_rnn, b_rnn);

    // --- SRU layer 1 ---
    gemm_kernel<1><<<dim3(125, 12), 256, 0, stream>>>(X1, W2T1, H_, 16, H3, U, nullptr, H3, nullptr, nullptr);
    sru_scan<<<dim3(128), 64, 0, stream>>>(U, X1, X2, v_rnn + 1024, b_rnn + 1024);

    // --- conv + tanh + maxpool fused, producing final-GEMM A matrix ---
    conv_pool<<<dim3(16 * 63 * 8), 256, 0, stream>>>(X2, conv_k, conv_b, A3);

    // --- G3: out = sigmoid(A3 @ W_out[:,257:514] + b_out[257:514]) * inputs[:,:,257:514] ---
    gemm_kernel<2><<<dim3(125, 3), 256, 0, stream>>>(A3, W3T, KHID, 144, NOUT, nullptr, out, NOUT, b_out + 257, inputs);
}